// Round 5
// baseline (594.765 us; speedup 1.0000x reference)
//
#include <hip/hip_runtime.h>

#define HW_N 1048576
#define C_IN 64
#define K_CLS 4096
#define H1_N 256
#define NCLS_N 16
#define CNT_BLOCKS 256
#define ROWS_PER_CNT (HW_N / CNT_BLOCKS)   // 4096
#define CPB 2                              // clusters per gather block

__device__ __forceinline__ float silu_f(float x) {
  return x / (1.0f + expf(-x));
}

// Degree-3 B-spline bases on the uniform grid g[j] = 0.4*(j-3) - 1, j=0..11.
__device__ __forceinline__ void bspline8(float x, float* b) {
  float t[11];
#pragma unroll
  for (int j = 0; j < 11; ++j) {
    float g0 = 0.4f * (float)(j - 3) - 1.0f;
    float g1 = 0.4f * (float)(j - 2) - 1.0f;
    t[j] = (x >= g0 && x < g1) ? 1.0f : 0.0f;
  }
#pragma unroll
  for (int k = 1; k <= 3; ++k) {
#pragma unroll 10
    for (int j = 0; j + k < 11; ++j) {
      float gj   = 0.4f * (float)(j - 3) - 1.0f;
      float gj1  = 0.4f * (float)(j - 2) - 1.0f;
      float gjk  = 0.4f * (float)(j + k - 3) - 1.0f;
      float gjk1 = 0.4f * (float)(j + k - 2) - 1.0f;
      float left  = (x - gj) / (gjk - gj);
      float right = (gjk1 - x) / (gjk1 - gj1);
      t[j] = left * t[j] + right * t[j + 1];
    }
  }
#pragma unroll
  for (int g = 0; g < 8; ++g) b[g] = t[g];
}

// ---- Stage A: per-block cluster histograms of cls -> bcnt[b][c] ----
__global__ __launch_bounds__(1024) void segcnt(
    const int* __restrict__ cls, int* __restrict__ bcnt) {
  __shared__ int chist[K_CLS];  // 16 KB
  int tid = threadIdx.x, b = blockIdx.x;
  for (int p = tid; p < K_CLS; p += 1024) chist[p] = 0;
  __syncthreads();
  int r0 = b * ROWS_PER_CNT;
  for (int r = r0 + tid; r < r0 + ROWS_PER_CNT; r += 1024)
    atomicAdd(&chist[cls[r]], 1);
  __syncthreads();
  int* dst = bcnt + b * K_CLS;
  for (int p = tid; p < K_CLS; p += 1024) dst[p] = chist[p];
}

// ---- Stage B1: per-cluster exclusive prefix over blocks ----
__global__ __launch_bounds__(256) void scan_blocks(
    const int* __restrict__ bcnt, int* __restrict__ bboff, int* __restrict__ tot) {
  int c = blockIdx.x * 256 + threadIdx.x;
  int run = 0;
#pragma unroll 8
  for (int b = 0; b < CNT_BLOCKS; ++b) {
    int v = bcnt[b * K_CLS + c];
    bboff[b * K_CLS + c] = run;
    run += v;
  }
  tot[c] = run;
}

// ---- Stage B2: exclusive scan over 4096 cluster totals -> base, cnt ----
__global__ __launch_bounds__(1024) void scan_clusters(
    const int* __restrict__ tot, int* __restrict__ base_, int* __restrict__ cnt) {
  __shared__ int wsum[16];
  int t = threadIdx.x;
  int c0 = t * 4;
  int v0 = tot[c0], v1 = tot[c0 + 1], v2 = tot[c0 + 2], v3 = tot[c0 + 3];
  int s = v0 + v1 + v2 + v3;
  int lane = t & 63, wave = t >> 6;
  int inc = s;
#pragma unroll
  for (int d = 1; d < 64; d <<= 1) {
    int o = __shfl_up(inc, d);
    if (lane >= d) inc += o;
  }
  if (lane == 63) wsum[wave] = inc;
  __syncthreads();
  if (t == 0) {
    int run = 0;
#pragma unroll
    for (int w = 0; w < 16; ++w) { int x_ = wsum[w]; wsum[w] = run; run += x_; }
  }
  __syncthreads();
  int excl = wsum[wave] + inc - s;
  base_[c0]     = excl;
  base_[c0 + 1] = excl + v0;
  base_[c0 + 2] = excl + v0 + v1;
  base_[c0 + 3] = excl + v0 + v1 + v2;
  cnt[c0] = v0; cnt[c0 + 1] = v1; cnt[c0 + 2] = v2; cnt[c0 + 3] = v3;
}

// ---- Stage C: scatter packed keys (row<<12 | cls) into sorted order ----
__global__ __launch_bounds__(1024) void scatter_idx(
    const int* __restrict__ cls, const int* __restrict__ bboff,
    const int* __restrict__ base_, int* __restrict__ spk) {
  __shared__ int lhist[K_CLS];  // 16 KB
  int b = blockIdx.x, tid = threadIdx.x;
  for (int c = tid; c < K_CLS; c += 1024)
    lhist[c] = bboff[b * K_CLS + c] + base_[c];
  __syncthreads();
  int r0 = b * ROWS_PER_CNT;
  for (int r = r0 + tid; r < r0 + ROWS_PER_CNT; r += 1024) {
    int c = cls[r];
    int pos = atomicAdd(&lhist[c], 1);
    spk[pos] = (r << 12) | c;
  }
}

// ---- Stage D: gather rows in sorted order, accumulate into sums ----
// 2048 blocks x 256 thr; block b owns clusters [b*CPB, b*CPB+CPB) and the
// sorted positions base_[c0]..end. Branch-free hot loop: every row lands in
// hist[CPB][64] (512 B). Flush = plain exclusive stores (no atomics, no memset).
__global__ __launch_bounds__(256) void gather_sum(
    const float* __restrict__ x, const int* __restrict__ spk,
    const int* __restrict__ base_, float* __restrict__ sums) {
  __shared__ float hist[CPB * C_IN];  // 512 B
  int c0 = blockIdx.x * CPB;
  int tid = threadIdx.x, wave = tid >> 6, lane = tid & 63;
  for (int p = tid; p < CPB * C_IN; p += 256) hist[p] = 0.0f;
  __syncthreads();
  int start = base_[c0];
  int end = (c0 + CPB < K_CLS) ? base_[c0 + CPB] : HW_N;

  for (int ch = start + wave * 64; ch < end; ch += 4 * 64) {
    int n = end - ch; n = n > 64 ? 64 : n;
    int pkreg = 0;
    if (lane < n) pkreg = spk[ch + lane];

    int j = 0;
    for (; j + 8 <= n; j += 8) {
      int pk[8];
#pragma unroll
      for (int k = 0; k < 8; ++k) pk[k] = __shfl(pkreg, j + k);
      float v[8];
#pragma unroll
      for (int k = 0; k < 8; ++k)
        v[k] = x[(size_t)(((unsigned)pk[k]) >> 12) * C_IN + lane];
#pragma unroll
      for (int k = 0; k < 8; ++k) {
        int rc = (pk[k] & (K_CLS - 1)) - c0;  // always in [0, CPB)
        atomicAdd(&hist[rc * C_IN + lane], v[k]);
      }
    }
    for (; j < n; ++j) {  // tail (< 8 rows)
      int pk = __shfl(pkreg, j);
      float v = x[(size_t)(((unsigned)pk) >> 12) * C_IN + lane];
      int rc = (pk & (K_CLS - 1)) - c0;
      atomicAdd(&hist[rc * C_IN + lane], v);
    }
  }
  __syncthreads();
  for (int p = tid; p < CPB * C_IN; p += 256)
    sums[(size_t)c0 * C_IN + p] = hist[p];
}

// ---------------- KAN layer 1 (64 -> 256) ----------------
__global__ __launch_bounds__(256) void kan1(
    const float* __restrict__ sums, const int* __restrict__ cnt,
    const float* __restrict__ bw1, const float* __restrict__ sw1,
    const float* __restrict__ sc1, float* __restrict__ h) {
  __shared__ float s_silu[8][64];      // 2 KB
  __shared__ float s_bases[8][64][8];  // 16 KB
  int row0 = blockIdx.x * 8;
  int tid = threadIdx.x;

  for (int p = tid; p < 8 * 64; p += 256) {
    int r = p >> 6, i = p & 63;
    float c = fmaxf((float)cnt[row0 + r], 1.0f);
    float xv = sums[(row0 + r) * C_IN + i] / c;
    s_silu[r][i] = silu_f(xv);
    float b[8];
    bspline8(xv, b);
    float4* dst = (float4*)&s_bases[r][i][0];
    dst[0] = make_float4(b[0], b[1], b[2], b[3]);
    dst[1] = make_float4(b[4], b[5], b[6], b[7]);
  }
  __syncthreads();

  int o = tid;
  float acc[8];
#pragma unroll
  for (int r = 0; r < 8; ++r) acc[r] = 0.0f;

  for (int i = 0; i < C_IN; ++i) {
    float wb  = bw1[o * C_IN + i];
    float wsc = sc1[o * C_IN + i];
    const float4* wp = (const float4*)&sw1[(o * C_IN + i) * 8];
    float4 w0 = wp[0], w1 = wp[1];
    w0.x *= wsc; w0.y *= wsc; w0.z *= wsc; w0.w *= wsc;
    w1.x *= wsc; w1.y *= wsc; w1.z *= wsc; w1.w *= wsc;
#pragma unroll
    for (int r = 0; r < 8; ++r) {
      float sv = s_silu[r][i];
      const float4* bp = (const float4*)&s_bases[r][i][0];
      float4 b0 = bp[0], b1 = bp[1];
      float a = acc[r];
      a = fmaf(sv, wb, a);
      a = fmaf(b0.x, w0.x, a); a = fmaf(b0.y, w0.y, a);
      a = fmaf(b0.z, w0.z, a); a = fmaf(b0.w, w0.w, a);
      a = fmaf(b1.x, w1.x, a); a = fmaf(b1.y, w1.y, a);
      a = fmaf(b1.z, w1.z, a); a = fmaf(b1.w, w1.w, a);
      acc[r] = a;
    }
  }
#pragma unroll
  for (int r = 0; r < 8; ++r) h[(row0 + r) * H1_N + o] = acc[r];
}

// ---------------- KAN layer 2 (256 -> 16) ----------------
__global__ __launch_bounds__(256) void kan2(
    const float* __restrict__ h,
    const float* __restrict__ bw2, const float* __restrict__ sw2,
    const float* __restrict__ sc2, float* __restrict__ out) {
  __shared__ float s_silu[16][65];
  __shared__ float s_bases[16][516];
  int row0 = blockIdx.x * 16;
  int tid = threadIdx.x;
  int o = tid & 15, rr = tid >> 4;
  float acc = 0.0f;

  for (int ic0 = 0; ic0 < H1_N; ic0 += 64) {
    for (int p = tid; p < 16 * 64; p += 256) {
      int r = p >> 6, i = p & 63;
      float xv = h[(row0 + r) * H1_N + ic0 + i];
      s_silu[r][i] = silu_f(xv);
      float b[8];
      bspline8(xv, b);
      float4* dst = (float4*)&s_bases[r][i * 8];
      dst[0] = make_float4(b[0], b[1], b[2], b[3]);
      dst[1] = make_float4(b[4], b[5], b[6], b[7]);
    }
    __syncthreads();

    for (int i = 0; i < 64; ++i) {
      int gi = ic0 + i;
      float wb  = bw2[o * H1_N + gi];
      float wsc = sc2[o * H1_N + gi];
      const float4* wp = (const float4*)&sw2[(o * H1_N + gi) * 8];
      float4 w0 = wp[0], w1 = wp[1];
      float sv = s_silu[rr][i];
      const float4* bp = (const float4*)&s_bases[rr][i * 8];
      float4 b0 = bp[0], b1 = bp[1];
      float sp = b0.x * w0.x + b0.y * w0.y + b0.z * w0.z + b0.w * w0.w
               + b1.x * w1.x + b1.y * w1.y + b1.z * w1.z + b1.w * w1.w;
      acc = fmaf(sv, wb, acc);
      acc = fmaf(sp, wsc, acc);
    }
    __syncthreads();
  }
  out[(row0 + rr) * NCLS_N + o] = acc;
}

extern "C" void kernel_launch(void* const* d_in, const int* in_sizes, int n_in,
                              void* d_out, int out_size, void* d_ws, size_t ws_size,
                              hipStream_t stream) {
  const float* x   = (const float*)d_in[0];
  const int*   cls = (const int*)d_in[1];
  const float* bw1 = (const float*)d_in[2];
  const float* sw1 = (const float*)d_in[3];
  const float* sc1 = (const float*)d_in[4];
  const float* bw2 = (const float*)d_in[5];
  const float* sw2 = (const float*)d_in[6];
  const float* sc2 = (const float*)d_in[7];
  float* out = (float*)d_out;

  float* sums  = (float*)d_ws;                 // 4096*64 f   (1 MB)
  int*   cnt   = (int*)(sums + K_CLS * C_IN);  // 4096
  int*   bcnt  = cnt + K_CLS;                  // 256*4096    (4 MB)
  int*   bboff = bcnt + CNT_BLOCKS * K_CLS;    // 256*4096    (4 MB)
  int*   tot   = bboff + CNT_BLOCKS * K_CLS;   // 4096
  int*   base_ = tot + K_CLS;                  // 4096
  int*   spk   = base_ + K_CLS;                // 1048576     (4 MB)
  float* h     = (float*)(spk + HW_N);         // 4096*256 f  (4 MB)

  segcnt<<<CNT_BLOCKS, 1024, 0, stream>>>(cls, bcnt);
  scan_blocks<<<K_CLS / 256, 256, 0, stream>>>(bcnt, bboff, tot);
  scan_clusters<<<1, 1024, 0, stream>>>(tot, base_, cnt);
  scatter_idx<<<CNT_BLOCKS, 1024, 0, stream>>>(cls, bboff, base_, spk);
  gather_sum<<<K_CLS / CPB, 256, 0, stream>>>(x, spk, base_, sums);
  kan1<<<K_CLS / 8, 256, 0, stream>>>(sums, cnt, bw1, sw1, sc1, h);
  kan2<<<K_CLS / 16, 256, 0, stream>>>(h, bw2, sw2, sc2, out);
}

// Round 6
// 279.090 us; speedup vs baseline: 2.1311x; 2.1311x over previous
//
#include <hip/hip_runtime.h>

#define HW_N 1048576
#define C_IN 64
#define K_CLS 4096
#define H1_N 256
#define NCLS_N 16
#define CNT_BLOCKS 256
#define ROWS_PER_CNT (HW_N / CNT_BLOCKS)   // 4096

__device__ __forceinline__ float silu_f(float x) {
  return x / (1.0f + expf(-x));
}

// Degree-3 B-spline bases on the uniform grid g[j] = 0.4*(j-3) - 1, j=0..11.
__device__ __forceinline__ void bspline8(float x, float* b) {
  float t[11];
#pragma unroll
  for (int j = 0; j < 11; ++j) {
    float g0 = 0.4f * (float)(j - 3) - 1.0f;
    float g1 = 0.4f * (float)(j - 2) - 1.0f;
    t[j] = (x >= g0 && x < g1) ? 1.0f : 0.0f;
  }
#pragma unroll
  for (int k = 1; k <= 3; ++k) {
#pragma unroll 10
    for (int j = 0; j + k < 11; ++j) {
      float gj   = 0.4f * (float)(j - 3) - 1.0f;
      float gj1  = 0.4f * (float)(j - 2) - 1.0f;
      float gjk  = 0.4f * (float)(j + k - 3) - 1.0f;
      float gjk1 = 0.4f * (float)(j + k - 2) - 1.0f;
      float left  = (x - gj) / (gjk - gj);
      float right = (gjk1 - x) / (gjk1 - gj1);
      t[j] = left * t[j] + right * t[j + 1];
    }
  }
#pragma unroll
  for (int g = 0; g < 8; ++g) b[g] = t[g];
}

// ---- Stage A: per-block cluster histograms of cls -> bcnt[b][c] ----
__global__ __launch_bounds__(1024) void segcnt(
    const int* __restrict__ cls, int* __restrict__ bcnt) {
  __shared__ int chist[K_CLS];  // 16 KB
  int tid = threadIdx.x, b = blockIdx.x;
  for (int p = tid; p < K_CLS; p += 1024) chist[p] = 0;
  __syncthreads();
  int r0 = b * ROWS_PER_CNT;
  for (int r = r0 + tid; r < r0 + ROWS_PER_CNT; r += 1024)
    atomicAdd(&chist[cls[r]], 1);
  __syncthreads();
  int* dst = bcnt + b * K_CLS;
  for (int p = tid; p < K_CLS; p += 1024) dst[p] = chist[p];
}

// ---- Stage B1: per-cluster exclusive prefix over blocks ----
__global__ __launch_bounds__(256) void scan_blocks(
    const int* __restrict__ bcnt, int* __restrict__ bboff, int* __restrict__ tot) {
  int c = blockIdx.x * 256 + threadIdx.x;
  int run = 0;
#pragma unroll 8
  for (int b = 0; b < CNT_BLOCKS; ++b) {
    int v = bcnt[b * K_CLS + c];
    bboff[b * K_CLS + c] = run;
    run += v;
  }
  tot[c] = run;
}

// ---- Stage B2: exclusive scan over 4096 cluster totals -> base, cnt ----
__global__ __launch_bounds__(1024) void scan_clusters(
    const int* __restrict__ tot, int* __restrict__ base_, int* __restrict__ cnt) {
  __shared__ int wsum[16];
  int t = threadIdx.x;
  int c0 = t * 4;
  int v0 = tot[c0], v1 = tot[c0 + 1], v2 = tot[c0 + 2], v3 = tot[c0 + 3];
  int s = v0 + v1 + v2 + v3;
  int lane = t & 63, wave = t >> 6;
  int inc = s;
#pragma unroll
  for (int d = 1; d < 64; d <<= 1) {
    int o = __shfl_up(inc, d);
    if (lane >= d) inc += o;
  }
  if (lane == 63) wsum[wave] = inc;
  __syncthreads();
  if (t == 0) {
    int run = 0;
#pragma unroll
    for (int w = 0; w < 16; ++w) { int x_ = wsum[w]; wsum[w] = run; run += x_; }
  }
  __syncthreads();
  int excl = wsum[wave] + inc - s;
  base_[c0]     = excl;
  base_[c0 + 1] = excl + v0;
  base_[c0 + 2] = excl + v0 + v1;
  base_[c0 + 3] = excl + v0 + v1 + v2;
  cnt[c0] = v0; cnt[c0 + 1] = v1; cnt[c0 + 2] = v2; cnt[c0 + 3] = v3;
}

// ---- Stage C: scatter packed keys (row<<12 | cls) into sorted order ----
__global__ __launch_bounds__(1024) void scatter_idx(
    const int* __restrict__ cls, const int* __restrict__ bboff,
    const int* __restrict__ base_, int* __restrict__ spk) {
  __shared__ int lhist[K_CLS];  // 16 KB
  int b = blockIdx.x, tid = threadIdx.x;
  for (int c = tid; c < K_CLS; c += 1024)
    lhist[c] = bboff[b * K_CLS + c] + base_[c];
  __syncthreads();
  int r0 = b * ROWS_PER_CNT;
  for (int r = r0 + tid; r < r0 + ROWS_PER_CNT; r += 1024) {
    int c = cls[r];
    int pos = atomicAdd(&lhist[c], 1);
    spk[pos] = (r << 12) | c;
  }
}

// ---- Stage D: gather rows, register-accumulate -> sums ----
// One block per cluster. Thread (g,q) = (tid>>4, tid&15): accumulates float4
// column q of rows i = g, g+16, ... into a register. Hot loop = pure
// global loads + fadds (no LDS, no shfl, no atomics), manually 8-deep.
__global__ __launch_bounds__(256, 2) void gather_sum(
    const float* __restrict__ x, const int* __restrict__ spk,
    const int* __restrict__ base_, const int* __restrict__ cnt,
    float* __restrict__ sums) {
  __shared__ float4 sacc[16][16];  // [g][q], 4 KB
  int c = blockIdx.x;
  int tid = threadIdx.x;
  int q = tid & 15, g = tid >> 4;
  int s = base_[c], n = cnt[c];
  const float4* x4 = (const float4*)x;  // row r at x4[r*16 + q]
  const int* sp = spk + s;

  float ax = 0.0f, ay = 0.0f, az = 0.0f, aw = 0.0f;
  int i = g;
  // 8-deep pipelined main loop: 8 independent idx loads, 8 independent
  // dwordx4 loads, then a pairwise add tree.
  for (; i + 112 < n; i += 128) {
    int p0 = sp[i];
    int p1 = sp[i + 16];
    int p2 = sp[i + 32];
    int p3 = sp[i + 48];
    int p4 = sp[i + 64];
    int p5 = sp[i + 80];
    int p6 = sp[i + 96];
    int p7 = sp[i + 112];
    float4 v0 = x4[(size_t)((unsigned)p0 >> 12) * 16 + q];
    float4 v1 = x4[(size_t)((unsigned)p1 >> 12) * 16 + q];
    float4 v2 = x4[(size_t)((unsigned)p2 >> 12) * 16 + q];
    float4 v3 = x4[(size_t)((unsigned)p3 >> 12) * 16 + q];
    float4 v4 = x4[(size_t)((unsigned)p4 >> 12) * 16 + q];
    float4 v5 = x4[(size_t)((unsigned)p5 >> 12) * 16 + q];
    float4 v6 = x4[(size_t)((unsigned)p6 >> 12) * 16 + q];
    float4 v7 = x4[(size_t)((unsigned)p7 >> 12) * 16 + q];
    float tx0 = v0.x + v1.x, tx1 = v2.x + v3.x, tx2 = v4.x + v5.x, tx3 = v6.x + v7.x;
    float ty0 = v0.y + v1.y, ty1 = v2.y + v3.y, ty2 = v4.y + v5.y, ty3 = v6.y + v7.y;
    float tz0 = v0.z + v1.z, tz1 = v2.z + v3.z, tz2 = v4.z + v5.z, tz3 = v6.z + v7.z;
    float tw0 = v0.w + v1.w, tw1 = v2.w + v3.w, tw2 = v4.w + v5.w, tw3 = v6.w + v7.w;
    ax += (tx0 + tx1) + (tx2 + tx3);
    ay += (ty0 + ty1) + (ty2 + ty3);
    az += (tz0 + tz1) + (tz2 + tz3);
    aw += (tw0 + tw1) + (tw2 + tw3);
  }
  for (; i < n; i += 16) {
    int p = sp[i];
    float4 v = x4[(size_t)((unsigned)p >> 12) * 16 + q];
    ax += v.x; ay += v.y; az += v.z; aw += v.w;
  }
  sacc[g][q] = make_float4(ax, ay, az, aw);
  __syncthreads();

  if (tid < 64) {  // f = tid
    const float* sa = (const float*)&sacc[0][0];
    int off = (tid >> 2) * 4 + (tid & 3);  // = tid
    float ssum = 0.0f;
#pragma unroll
    for (int gg = 0; gg < 16; ++gg) ssum += sa[gg * 64 + off];
    sums[(size_t)c * C_IN + tid] = ssum;
  }
}

// ---------------- KAN layer 1 (64 -> 256) ----------------
__global__ __launch_bounds__(256) void kan1(
    const float* __restrict__ sums, const int* __restrict__ cnt,
    const float* __restrict__ bw1, const float* __restrict__ sw1,
    const float* __restrict__ sc1, float* __restrict__ h) {
  __shared__ float s_silu[8][64];      // 2 KB
  __shared__ float s_bases[8][64][8];  // 16 KB
  int row0 = blockIdx.x * 8;
  int tid = threadIdx.x;

  for (int p = tid; p < 8 * 64; p += 256) {
    int r = p >> 6, i = p & 63;
    float c = fmaxf((float)cnt[row0 + r], 1.0f);
    float xv = sums[(row0 + r) * C_IN + i] / c;
    s_silu[r][i] = silu_f(xv);
    float b[8];
    bspline8(xv, b);
    float4* dst = (float4*)&s_bases[r][i][0];
    dst[0] = make_float4(b[0], b[1], b[2], b[3]);
    dst[1] = make_float4(b[4], b[5], b[6], b[7]);
  }
  __syncthreads();

  int o = tid;
  float acc[8];
#pragma unroll
  for (int r = 0; r < 8; ++r) acc[r] = 0.0f;

  for (int i = 0; i < C_IN; ++i) {
    float wb  = bw1[o * C_IN + i];
    float wsc = sc1[o * C_IN + i];
    const float4* wp = (const float4*)&sw1[(o * C_IN + i) * 8];
    float4 w0 = wp[0], w1 = wp[1];
    w0.x *= wsc; w0.y *= wsc; w0.z *= wsc; w0.w *= wsc;
    w1.x *= wsc; w1.y *= wsc; w1.z *= wsc; w1.w *= wsc;
#pragma unroll
    for (int r = 0; r < 8; ++r) {
      float sv = s_silu[r][i];
      const float4* bp = (const float4*)&s_bases[r][i][0];
      float4 b0 = bp[0], b1 = bp[1];
      float a = acc[r];
      a = fmaf(sv, wb, a);
      a = fmaf(b0.x, w0.x, a); a = fmaf(b0.y, w0.y, a);
      a = fmaf(b0.z, w0.z, a); a = fmaf(b0.w, w0.w, a);
      a = fmaf(b1.x, w1.x, a); a = fmaf(b1.y, w1.y, a);
      a = fmaf(b1.z, w1.z, a); a = fmaf(b1.w, w1.w, a);
      acc[r] = a;
    }
  }
#pragma unroll
  for (int r = 0; r < 8; ++r) h[(row0 + r) * H1_N + o] = acc[r];
}

// ---------------- KAN layer 2 (256 -> 16) ----------------
__global__ __launch_bounds__(256) void kan2(
    const float* __restrict__ h,
    const float* __restrict__ bw2, const float* __restrict__ sw2,
    const float* __restrict__ sc2, float* __restrict__ out) {
  __shared__ float s_silu[16][65];
  __shared__ float s_bases[16][516];
  int row0 = blockIdx.x * 16;
  int tid = threadIdx.x;
  int o = tid & 15, rr = tid >> 4;
  float acc = 0.0f;

  for (int ic0 = 0; ic0 < H1_N; ic0 += 64) {
    for (int p = tid; p < 16 * 64; p += 256) {
      int r = p >> 6, i = p & 63;
      float xv = h[(row0 + r) * H1_N + ic0 + i];
      s_silu[r][i] = silu_f(xv);
      float b[8];
      bspline8(xv, b);
      float4* dst = (float4*)&s_bases[r][i * 8];
      dst[0] = make_float4(b[0], b[1], b[2], b[3]);
      dst[1] = make_float4(b[4], b[5], b[6], b[7]);
    }
    __syncthreads();

    for (int i = 0; i < 64; ++i) {
      int gi = ic0 + i;
      float wb  = bw2[o * H1_N + gi];
      float wsc = sc2[o * H1_N + gi];
      const float4* wp = (const float4*)&sw2[(o * H1_N + gi) * 8];
      float4 w0 = wp[0], w1 = wp[1];
      float sv = s_silu[rr][i];
      const float4* bp = (const float4*)&s_bases[rr][i * 8];
      float4 b0 = bp[0], b1 = bp[1];
      float sp = b0.x * w0.x + b0.y * w0.y + b0.z * w0.z + b0.w * w0.w
               + b1.x * w1.x + b1.y * w1.y + b1.z * w1.z + b1.w * w1.w;
      acc = fmaf(sv, wb, acc);
      acc = fmaf(sp, wsc, acc);
    }
    __syncthreads();
  }
  out[(row0 + rr) * NCLS_N + o] = acc;
}

extern "C" void kernel_launch(void* const* d_in, const int* in_sizes, int n_in,
                              void* d_out, int out_size, void* d_ws, size_t ws_size,
                              hipStream_t stream) {
  const float* x   = (const float*)d_in[0];
  const int*   cls = (const int*)d_in[1];
  const float* bw1 = (const float*)d_in[2];
  const float* sw1 = (const float*)d_in[3];
  const float* sc1 = (const float*)d_in[4];
  const float* bw2 = (const float*)d_in[5];
  const float* sw2 = (const float*)d_in[6];
  const float* sc2 = (const float*)d_in[7];
  float* out = (float*)d_out;

  float* sums  = (float*)d_ws;                 // 4096*64 f   (1 MB)
  int*   cnt   = (int*)(sums + K_CLS * C_IN);  // 4096
  int*   bcnt  = cnt + K_CLS;                  // 256*4096    (4 MB)
  int*   bboff = bcnt + CNT_BLOCKS * K_CLS;    // 256*4096    (4 MB)
  int*   tot   = bboff + CNT_BLOCKS * K_CLS;   // 4096
  int*   base_ = tot + K_CLS;                  // 4096
  int*   spk   = base_ + K_CLS;                // 1048576     (4 MB)
  float* h     = (float*)(spk + HW_N);         // 4096*256 f  (4 MB)

  segcnt<<<CNT_BLOCKS, 1024, 0, stream>>>(cls, bcnt);
  scan_blocks<<<K_CLS / 256, 256, 0, stream>>>(bcnt, bboff, tot);
  scan_clusters<<<1, 1024, 0, stream>>>(tot, base_, cnt);
  scatter_idx<<<CNT_BLOCKS, 1024, 0, stream>>>(cls, bboff, base_, spk);
  gather_sum<<<K_CLS, 256, 0, stream>>>(x, spk, base_, cnt, sums);
  kan1<<<K_CLS / 8, 256, 0, stream>>>(sums, cnt, bw1, sw1, sc1, h);
  kan2<<<K_CLS / 16, 256, 0, stream>>>(h, bw2, sw2, sc2, out);
}

// Round 7
// 178.714 us; speedup vs baseline: 3.3280x; 1.5617x over previous
//
#include <hip/hip_runtime.h>

#define HW_N 1048576
#define C_IN 64
#define K_CLS 4096
#define H1_N 256
#define NCLS_N 16
#define CNT_BLOCKS 256
#define ROWS_PER_CNT (HW_N / CNT_BLOCKS)   // 4096

__device__ __forceinline__ float silu_f(float x) {
  return x / (1.0f + expf(-x));
}

// Degree-3 B-spline bases on the uniform grid g[j] = 0.4*(j-3) - 1, j=0..11.
__device__ __forceinline__ void bspline8(float x, float* b) {
  float t[11];
#pragma unroll
  for (int j = 0; j < 11; ++j) {
    float g0 = 0.4f * (float)(j - 3) - 1.0f;
    float g1 = 0.4f * (float)(j - 2) - 1.0f;
    t[j] = (x >= g0 && x < g1) ? 1.0f : 0.0f;
  }
#pragma unroll
  for (int k = 1; k <= 3; ++k) {
#pragma unroll 10
    for (int j = 0; j + k < 11; ++j) {
      float gj   = 0.4f * (float)(j - 3) - 1.0f;
      float gj1  = 0.4f * (float)(j - 2) - 1.0f;
      float gjk  = 0.4f * (float)(j + k - 3) - 1.0f;
      float gjk1 = 0.4f * (float)(j + k - 2) - 1.0f;
      float left  = (x - gj) / (gjk - gj);
      float right = (gjk1 - x) / (gjk1 - gj1);
      t[j] = left * t[j] + right * t[j + 1];
    }
  }
#pragma unroll
  for (int g = 0; g < 8; ++g) b[g] = t[g];
}

// ---- Weight transposes (one-time per launch, pre-scaled by spline_scaler) ----
// swt1[i][o][e] = sw1[o][i][e] * sc1[o][i];  bwt1[i][o] = bw1[o][i]
__global__ __launch_bounds__(256) void transpose_w1(
    const float* __restrict__ bw1, const float* __restrict__ sw1,
    const float* __restrict__ sc1, float* __restrict__ bwt1,
    float* __restrict__ swt1) {
  int i = blockIdx.x;      // 0..63
  int o = threadIdx.x;     // 0..255
  float sc = sc1[o * C_IN + i];
  bwt1[i * H1_N + o] = bw1[o * C_IN + i];
  const float4* src = (const float4*)&sw1[(size_t)(o * C_IN + i) * 8];
  float4 a = src[0], b = src[1];
  a.x *= sc; a.y *= sc; a.z *= sc; a.w *= sc;
  b.x *= sc; b.y *= sc; b.z *= sc; b.w *= sc;
  float4* dst = (float4*)&swt1[(size_t)(i * H1_N + o) * 8];
  dst[0] = a; dst[1] = b;
}

// swt2[gi][o][e] = sw2[o][gi][e] * sc2[o][gi];  bwt2[gi][o] = bw2[o][gi]
__global__ __launch_bounds__(128) void transpose_w2(
    const float* __restrict__ bw2, const float* __restrict__ sw2,
    const float* __restrict__ sc2, float* __restrict__ bwt2,
    float* __restrict__ swt2) {
  int gi = blockIdx.x;     // 0..255
  int tid = threadIdx.x;   // 0..127
  int o = tid >> 3, e = tid & 7;
  swt2[(gi * NCLS_N + o) * 8 + e] =
      sw2[(size_t)(o * H1_N + gi) * 8 + e] * sc2[o * H1_N + gi];
  if (tid < NCLS_N) bwt2[gi * NCLS_N + tid] = bw2[tid * H1_N + gi];
}

// ---- Stage A: per-block cluster histograms of cls -> bcnt[b][c] ----
__global__ __launch_bounds__(1024) void segcnt(
    const int* __restrict__ cls, int* __restrict__ bcnt) {
  __shared__ int chist[K_CLS];  // 16 KB
  int tid = threadIdx.x, b = blockIdx.x;
  for (int p = tid; p < K_CLS; p += 1024) chist[p] = 0;
  __syncthreads();
  int r0 = b * ROWS_PER_CNT;
  for (int r = r0 + tid; r < r0 + ROWS_PER_CNT; r += 1024)
    atomicAdd(&chist[cls[r]], 1);
  __syncthreads();
  int* dst = bcnt + b * K_CLS;
  for (int p = tid; p < K_CLS; p += 1024) dst[p] = chist[p];
}

// ---- Stage B1: per-cluster exclusive prefix over blocks ----
__global__ __launch_bounds__(256) void scan_blocks(
    const int* __restrict__ bcnt, int* __restrict__ bboff, int* __restrict__ tot) {
  int c = blockIdx.x * 256 + threadIdx.x;
  int run = 0;
#pragma unroll 8
  for (int b = 0; b < CNT_BLOCKS; ++b) {
    int v = bcnt[b * K_CLS + c];
    bboff[b * K_CLS + c] = run;
    run += v;
  }
  tot[c] = run;
}

// ---- Stage B2: exclusive scan over 4096 cluster totals -> base, cnt ----
__global__ __launch_bounds__(1024) void scan_clusters(
    const int* __restrict__ tot, int* __restrict__ base_, int* __restrict__ cnt) {
  __shared__ int wsum[16];
  int t = threadIdx.x;
  int c0 = t * 4;
  int v0 = tot[c0], v1 = tot[c0 + 1], v2 = tot[c0 + 2], v3 = tot[c0 + 3];
  int s = v0 + v1 + v2 + v3;
  int lane = t & 63, wave = t >> 6;
  int inc = s;
#pragma unroll
  for (int d = 1; d < 64; d <<= 1) {
    int o = __shfl_up(inc, d);
    if (lane >= d) inc += o;
  }
  if (lane == 63) wsum[wave] = inc;
  __syncthreads();
  if (t == 0) {
    int run = 0;
#pragma unroll
    for (int w = 0; w < 16; ++w) { int x_ = wsum[w]; wsum[w] = run; run += x_; }
  }
  __syncthreads();
  int excl = wsum[wave] + inc - s;
  base_[c0]     = excl;
  base_[c0 + 1] = excl + v0;
  base_[c0 + 2] = excl + v0 + v1;
  base_[c0 + 3] = excl + v0 + v1 + v2;
  cnt[c0] = v0; cnt[c0 + 1] = v1; cnt[c0 + 2] = v2; cnt[c0 + 3] = v3;
}

// ---- Stage C: scatter packed keys (row<<12 | cls) into sorted order ----
__global__ __launch_bounds__(1024) void scatter_idx(
    const int* __restrict__ cls, const int* __restrict__ bboff,
    const int* __restrict__ base_, int* __restrict__ spk) {
  __shared__ int lhist[K_CLS];  // 16 KB
  int b = blockIdx.x, tid = threadIdx.x;
  for (int c = tid; c < K_CLS; c += 1024)
    lhist[c] = bboff[b * K_CLS + c] + base_[c];
  __syncthreads();
  int r0 = b * ROWS_PER_CNT;
  for (int r = r0 + tid; r < r0 + ROWS_PER_CNT; r += 1024) {
    int c = cls[r];
    int pos = atomicAdd(&lhist[c], 1);
    spk[pos] = (r << 12) | c;
  }
}

// ---- Stage D: gather rows, register-accumulate -> mean (sums/cnt folded) ----
// One block per cluster. Thread (g,q) = (tid>>4, tid&15) accumulates float4
// column q of rows i = g, g+16, ... 4-deep pipelined (all threads stay in the
// main loop for typical n~256; tail <= 3 rows).
__global__ __launch_bounds__(256, 2) void gather_mean(
    const float* __restrict__ x, const int* __restrict__ spk,
    const int* __restrict__ base_, const int* __restrict__ cnt,
    float* __restrict__ mean) {
  __shared__ float4 sacc[16][16];  // [g][q], 4 KB
  int c = blockIdx.x;
  int tid = threadIdx.x;
  int q = tid & 15, g = tid >> 4;
  int s = base_[c], n = cnt[c];
  const float4* x4 = (const float4*)x;  // row r at x4[r*16 + q]
  const int* sp = spk + s;

  float ax = 0.0f, ay = 0.0f, az = 0.0f, aw = 0.0f;
  int i = g;
  for (; i + 48 < n; i += 64) {
    int p0 = sp[i];
    int p1 = sp[i + 16];
    int p2 = sp[i + 32];
    int p3 = sp[i + 48];
    float4 v0 = x4[(size_t)((unsigned)p0 >> 12) * 16 + q];
    float4 v1 = x4[(size_t)((unsigned)p1 >> 12) * 16 + q];
    float4 v2 = x4[(size_t)((unsigned)p2 >> 12) * 16 + q];
    float4 v3 = x4[(size_t)((unsigned)p3 >> 12) * 16 + q];
    ax += (v0.x + v1.x) + (v2.x + v3.x);
    ay += (v0.y + v1.y) + (v2.y + v3.y);
    az += (v0.z + v1.z) + (v2.z + v3.z);
    aw += (v0.w + v1.w) + (v2.w + v3.w);
  }
  for (; i < n; i += 16) {
    int p = sp[i];
    float4 v = x4[(size_t)((unsigned)p >> 12) * 16 + q];
    ax += v.x; ay += v.y; az += v.z; aw += v.w;
  }
  sacc[g][q] = make_float4(ax, ay, az, aw);
  __syncthreads();

  if (tid < 64) {  // f = tid
    const float* sa = (const float*)&sacc[0][0];
    float ssum = 0.0f;
#pragma unroll
    for (int gg = 0; gg < 16; ++gg) ssum += sa[gg * 64 + tid];
    float inv = 1.0f / fmaxf((float)n, 1.0f);
    mean[(size_t)c * C_IN + tid] = ssum * inv;
  }
}

// ---------------- KAN layer 1 (64 -> 256), transposed weights ----------------
__global__ __launch_bounds__(256) void kan1(
    const float* __restrict__ mean, const float* __restrict__ bwt1,
    const float* __restrict__ swt1, float* __restrict__ h) {
  __shared__ float s_silu[8][64];      // 2 KB
  __shared__ float s_bases[8][64][8];  // 16 KB
  int row0 = blockIdx.x * 8;
  int tid = threadIdx.x;

  for (int p = tid; p < 8 * 64; p += 256) {
    int r = p >> 6, i = p & 63;
    float xv = mean[(row0 + r) * C_IN + i];
    s_silu[r][i] = silu_f(xv);
    float b[8];
    bspline8(xv, b);
    float4* dst = (float4*)&s_bases[r][i][0];
    dst[0] = make_float4(b[0], b[1], b[2], b[3]);
    dst[1] = make_float4(b[4], b[5], b[6], b[7]);
  }
  __syncthreads();

  int o = tid;
  float acc[8];
#pragma unroll
  for (int r = 0; r < 8; ++r) acc[r] = 0.0f;

  for (int i = 0; i < C_IN; ++i) {
    float wb = bwt1[i * H1_N + o];                          // coalesced
    const float4* wp = (const float4*)&swt1[(size_t)(i * H1_N + o) * 8];
    float4 w0 = wp[0], w1 = wp[1];                          // pre-scaled
#pragma unroll
    for (int r = 0; r < 8; ++r) {
      float sv = s_silu[r][i];
      const float4* bp = (const float4*)&s_bases[r][i][0];
      float4 b0 = bp[0], b1 = bp[1];
      float a = acc[r];
      a = fmaf(sv, wb, a);
      a = fmaf(b0.x, w0.x, a); a = fmaf(b0.y, w0.y, a);
      a = fmaf(b0.z, w0.z, a); a = fmaf(b0.w, w0.w, a);
      a = fmaf(b1.x, w1.x, a); a = fmaf(b1.y, w1.y, a);
      a = fmaf(b1.z, w1.z, a); a = fmaf(b1.w, w1.w, a);
      acc[r] = a;
    }
  }
#pragma unroll
  for (int r = 0; r < 8; ++r) h[(row0 + r) * H1_N + o] = acc[r];
}

// ---------------- KAN layer 2 (256 -> 16), transposed weights ----------------
__global__ __launch_bounds__(256) void kan2(
    const float* __restrict__ h, const float* __restrict__ bwt2,
    const float* __restrict__ swt2, float* __restrict__ out) {
  __shared__ float s_silu[16][65];
  __shared__ float s_bases[16][516];
  int row0 = blockIdx.x * 16;
  int tid = threadIdx.x;
  int o = tid & 15, rr = tid >> 4;
  float acc = 0.0f;

  for (int ic0 = 0; ic0 < H1_N; ic0 += 64) {
    for (int p = tid; p < 16 * 64; p += 256) {
      int r = p >> 6, i = p & 63;
      float xv = h[(row0 + r) * H1_N + ic0 + i];
      s_silu[r][i] = silu_f(xv);
      float b[8];
      bspline8(xv, b);
      float4* dst = (float4*)&s_bases[r][i * 8];
      dst[0] = make_float4(b[0], b[1], b[2], b[3]);
      dst[1] = make_float4(b[4], b[5], b[6], b[7]);
    }
    __syncthreads();

    for (int i = 0; i < 64; ++i) {
      int gi = ic0 + i;
      float wb = bwt2[gi * NCLS_N + o];                     // 1-line/wave
      const float4* wp = (const float4*)&swt2[(gi * NCLS_N + o) * 8];
      float4 w0 = wp[0], w1 = wp[1];                        // pre-scaled
      float sv = s_silu[rr][i];
      const float4* bp = (const float4*)&s_bases[rr][i * 8];
      float4 b0 = bp[0], b1 = bp[1];
      float sp = b0.x * w0.x + b0.y * w0.y + b0.z * w0.z + b0.w * w0.w
               + b1.x * w1.x + b1.y * w1.y + b1.z * w1.z + b1.w * w1.w;
      acc = fmaf(sv, wb, acc);
      acc += sp;
    }
    __syncthreads();
  }
  out[(row0 + rr) * NCLS_N + o] = acc;
}

extern "C" void kernel_launch(void* const* d_in, const int* in_sizes, int n_in,
                              void* d_out, int out_size, void* d_ws, size_t ws_size,
                              hipStream_t stream) {
  const float* x   = (const float*)d_in[0];
  const int*   cls = (const int*)d_in[1];
  const float* bw1 = (const float*)d_in[2];
  const float* sw1 = (const float*)d_in[3];
  const float* sc1 = (const float*)d_in[4];
  const float* bw2 = (const float*)d_in[5];
  const float* sw2 = (const float*)d_in[6];
  const float* sc2 = (const float*)d_in[7];
  float* out = (float*)d_out;

  float* mean  = (float*)d_ws;                  // 4096*64 f   (1 MB)
  int*   cnt   = (int*)(mean + K_CLS * C_IN);   // 4096
  int*   bcnt  = cnt + K_CLS;                   // 256*4096    (4 MB)
  int*   bboff = bcnt + CNT_BLOCKS * K_CLS;     // 256*4096    (4 MB)
  int*   tot   = bboff + CNT_BLOCKS * K_CLS;    // 4096
  int*   base_ = tot + K_CLS;                   // 4096
  int*   spk   = base_ + K_CLS;                 // 1048576     (4 MB)
  float* h     = (float*)(spk + HW_N);          // 4096*256 f  (4 MB)
  float* swt1  = h + K_CLS * H1_N;              // 64*256*8    (512 KB)
  float* bwt1  = swt1 + C_IN * H1_N * 8;        // 64*256
  float* swt2  = bwt1 + C_IN * H1_N;            // 256*16*8    (128 KB)
  float* bwt2  = swt2 + H1_N * NCLS_N * 8;      // 256*16

  transpose_w1<<<C_IN, 256, 0, stream>>>(bw1, sw1, sc1, bwt1, swt1);
  transpose_w2<<<H1_N, 128, 0, stream>>>(bw2, sw2, sc2, bwt2, swt2);
  segcnt<<<CNT_BLOCKS, 1024, 0, stream>>>(cls, bcnt);
  scan_blocks<<<K_CLS / 256, 256, 0, stream>>>(bcnt, bboff, tot);
  scan_clusters<<<1, 1024, 0, stream>>>(tot, base_, cnt);
  scatter_idx<<<CNT_BLOCKS, 1024, 0, stream>>>(cls, bboff, base_, spk);
  gather_mean<<<K_CLS, 256, 0, stream>>>(x, spk, base_, cnt, mean);
  kan1<<<K_CLS / 8, 256, 0, stream>>>(mean, bwt1, swt1, h);
  kan2<<<K_CLS / 16, 256, 0, stream>>>(h, bwt2, swt2, out);
}